// Round 14
// baseline (2721.651 us; speedup 1.0000x reference)
//
#include <hip/hip_runtime.h>

#define SEQ 999
#define DTC 0.01f
#define NXW 125
#define NW1 64
#define IDX_C0  0
#define IDX_C1  32
#define IDX_CW1 64
#define IDX_FLG 96
#define SYNC_DWORDS 4096
#define XW0B 395264          // k_convert: xw0 work starts at this flat index

typedef _Float16 h2 __attribute__((ext_vector_type(2)));
typedef unsigned u32x4 __attribute__((ext_vector_type(4)));
typedef float f32x4 __attribute__((ext_vector_type(4)));

__device__ __forceinline__ h2 u2h(unsigned u){ return __builtin_bit_cast(h2,u); }
__device__ __forceinline__ h2 pkfma(h2 a, h2 b, h2 c){ return __builtin_elementwise_fma(a,b,c); }

__device__ __forceinline__ float softplusf(float x){
  return fmaxf(x,0.f) + log1pf(__expf(-fabsf(x)));
}
__device__ __forceinline__ float sigmoidf(float x){ return 1.f/(1.f+__expf(-x)); }
__device__ __forceinline__ float tanh_fast(float x){
  float e = __expf(-2.f*x); return (1.f-e)/(1.f+e);
}

template<int SLP>
__device__ __forceinline__ void waitge(unsigned* p, unsigned v){
  if (__hip_atomic_load(p,__ATOMIC_RELAXED,__HIP_MEMORY_SCOPE_AGENT) < v){
    do { __builtin_amdgcn_s_sleep(SLP); }
    while (__hip_atomic_load(p,__ATOMIC_RELAXED,__HIP_MEMORY_SCOPE_AGENT) < v);
  }
  (void)__hip_atomic_load(p,__ATOMIC_ACQUIRE,__HIP_MEMORY_SCOPE_AGENT);
}

__global__ void k_init(unsigned* sync){
  for (int i=threadIdx.x; i<SYNC_DWORDS; i+=512) sync[i] = 0u;
}

// Whh -> MFMA A-frags, INTERLEAVED rows (r13-proven): tile T rows = units 4T..4T+3
// x gates i,f,g,o. k-mapping r11/r12/r13-proven (absmax 0.0).
// wih1 -> TRANSPOSED (do_xw). xw0[t][unit][gate] precomputed.
__global__ void k_convert(const float* __restrict__ whh0, const float* __restrict__ wih1,
                          const float* __restrict__ whh1, const float* __restrict__ wih0,
                          const float* __restrict__ X,
                          const float* __restrict__ bih0, const float* __restrict__ bhh0,
                          const float* __restrict__ bih1, const float* __restrict__ bhh1,
                          h2* __restrict__ aW0, h2* __restrict__ wih1T, h2* __restrict__ aW1,
                          float* __restrict__ bs1, float* __restrict__ xw0){
  int o = blockIdx.x*256 + threadIdx.x;
  if (o < 131072){
    int f = o >> 8, rem = o & 255, l = rem >> 2, jp = rem & 3;
    int tile = f >> 3, q = f & 7;
    int rl = l & 15;
    int row = (rl & 3)*256 + tile*4 + (rl >> 2);
    int col = q*32 + ((l >> 4) << 3) + (jp << 1);
    const float* s = whh0 + row*256 + col;
    aW0[o] = h2{(_Float16)s[0], (_Float16)s[1]};
  } else if (o < 262144){
    int oo = o - 131072; int r = oo & 1023, c2 = oo >> 10;
    const float* s = wih1 + r*256 + 2*c2;
    wih1T[oo] = h2{(_Float16)s[0], (_Float16)s[1]};
  } else if (o < 393216){
    int oo = o - 262144;
    int f = oo >> 8, rem = oo & 255, l = rem >> 2, jp = rem & 3;
    int tile = f >> 3, q = f & 7;
    int rl = l & 15;
    int row = (rl & 3)*256 + tile*4 + (rl >> 2);
    int col = q*32 + ((l >> 4) << 3) + (jp << 1);
    const float* s = whh1 + row*256 + col;
    aW1[oo] = h2{(_Float16)s[0], (_Float16)s[1]};
  } else if (o < 394240){
    // spare
  } else if (o < XW0B){
    int r = o - 394240; bs1[r] = bih1[r] + bhh1[r];
  } else if (o < XW0B + SEQ*1024){
    int idx = o - XW0B;
    int t = idx >> 10, r = idx & 1023;
    int k = r >> 2, g = r & 3;
    int row = g*256 + k;
    float v = wih0[row*2]*X[2*t] + wih0[row*2+1]*X[2*t+1] + bih0[row] + bhh0[row];
    xw0[idx] = v;
  }
}

// ---- MFMA helpers ----
#define MMA(ACC,AG,BQ)  asm volatile("v_mfma_f32_16x16x32_f16 %0, %1, %2, %0" \
  : "+v"(ACC) : "a"(AG), "v"(BQ))
#define MML(ACC,W,BQ)   asm volatile("v_mfma_f32_16x16x32_f16 %0, %1, %2, %0" \
  : "+v"(ACC) : "v"(W), "v"(BQ))
#define MMAI(ACC,AG,BQ) asm volatile("v_mfma_f32_16x16x32_f16 %0, %1, %2, %3" \
  : "=&v"(ACC) : "a"(AG), "v"(BQ), "v"(zero4))
#define MMLI(ACC,W,BQ)  asm volatile("v_mfma_f32_16x16x32_f16 %0, %1, %2, %3" \
  : "=&v"(ACC) : "v"(W), "v"(BQ), "v"(zero4))

// Q-block: issue w-tile LDS reads FIRST (covered by 6 AGPR mfmas), prefetch next
// B-frag during this block (covered by ~8 mfmas). Loads are non-volatile C reads:
// compiler floats them across the volatile mfmas and emits fine-grained lgkmcnt.
#define QSTEP(Q) do{                                               \
  u32x4 w6 = aspill[wv][0][Q][lane];                               \
  u32x4 w7 = aspill[wv][1][Q][lane];                               \
  u32x4 BqN = *(const u32x4*)(hbp + ((Q)+1 < 8 ? (Q)+1 : 7)*64);   \
  MMA(ac0,agA[0][Q],Bq); MMA(ac1,agA[1][Q],Bq);                    \
  MMA(ac2,agA[2][Q],Bq); MMA(ac3,agA[3][Q],Bq);                    \
  MMA(ac4,agA[4][Q],Bq); MMA(ac5,agA[5][Q],Bq);                    \
  MML(ac6,w6,Bq);        MML(ac7,w7,Bq);                           \
  Bq = BqN;                                                        \
}while(0)

// ===== LSTM layer, ONE CU, MFMA, single barrier/step (r13 structure).
// 512 thr / 8 waves; wave owns tiles wv*8..+7 = units wv*32..+31 (interleaved gates).
// Residency: tiles 0-5 AGPR (192), tiles 6-7 LDS; arch regs only for accs+temps.
template<int GATED>   // 0: L0 (xw0), 1: L1 (xw1, chunk-flag gated)
__device__ void do_layer(const u32x4* __restrict__ wA, const float* __restrict__ xw,
                         _Float16* __restrict__ hOutHalf, float* __restrict__ hOutF32,
                         unsigned* prog, unsigned* sync,
                         u32x4 (*aspill)[2][8][64], f32x4 (*uscr)[32],
                         _Float16 (*hbufS)[256])
{
  const int tid  = threadIdx.x;
  const int lane = tid & 63;
  const int wv   = tid >> 6;
  const int m    = lane & 15;
  const int g4   = lane >> 4;
  const bool act = m < 8;
  const int unit = wv*32 + m*4 + g4;          // valid when act

  u32x4 agA[6][8];
#pragma unroll
  for (int tt=0;tt<6;++tt)
#pragma unroll
    for (int q=0;q<8;++q)
      agA[tt][q] = wA[(size_t)(((wv*8+tt)*8+q)*64) + lane];
#pragma unroll
  for (int tt=0;tt<6;++tt)
#pragma unroll
    for (int q=0;q<8;++q) asm("" : "+a"(agA[tt][q]));
#pragma unroll
  for (int tt=0;tt<2;++tt)
#pragma unroll
    for (int q=0;q<8;++q)
      aspill[wv][tt][q][lane] = wA[(size_t)(((wv*8+6+tt)*8+q)*64) + lane];

  if (tid < 256) hbufS[0][tid] = (_Float16)0.f;
  __syncthreads();

  if (GATED){
    if (tid==0) waitge<2>(&sync[IDX_FLG+0], 1u);
    __syncthreads();
  }

  f32x4 zero4 = {0.f,0.f,0.f,0.f};
  asm("" : "+v"(zero4));

  const char* hbb = (const char*)&hbufS[0][0] + (g4<<4);
  float c = 0.f;

#pragma unroll 1
  for (int t=0;t<SEQ;++t){
    if (GATED && (t&7)==0 && t){
      if (tid==0) waitge<2>(&sync[IDX_FLG + (t>>3)*32], 1u);
      __syncthreads();
    }
    float4 nx = {0,0,0,0};
    if (act) nx = *(const float4*)&xw[(size_t)t*1024 + (unit<<2)];   // returns during mfma

    const char* hbp = hbb + ((t&1)<<9);
    f32x4 ac0, ac1, ac2, ac3, ac4, ac5, ac6, ac7;

    // Q=0: init accumulators (zero4 C-operand), prefetch Q=1 B-frag
    u32x4 Bq = *(const u32x4*)(hbp);
    {
      u32x4 w6 = aspill[wv][0][0][lane];
      u32x4 w7 = aspill[wv][1][0][lane];
      u32x4 BqN = *(const u32x4*)(hbp + 64);
      MMAI(ac0,agA[0][0],Bq); MMAI(ac1,agA[1][0],Bq);
      MMAI(ac2,agA[2][0],Bq); MMAI(ac3,agA[3][0],Bq);
      MMAI(ac4,agA[4][0],Bq); MMAI(ac5,agA[5][0],Bq);
      MMLI(ac6,w6,Bq);        MMLI(ac7,w7,Bq);
      Bq = BqN;
    }
    QSTEP(1); QSTEP(2); QSTEP(3); QSTEP(4); QSTEP(5); QSTEP(6); QSTEP(7);
    asm volatile("s_nop 7\n\ts_nop 7");

    // dump accs to per-wave scratch (same-wave, no barrier needed)
    if (m == 0){
      f32x4* us = &uscr[wv][g4];
      us[0]  = ac0; us[4]  = ac1; us[8]  = ac2; us[12] = ac3;
      us[16] = ac4; us[20] = ac5; us[24] = ac6; us[28] = ac7;
    }
    asm volatile("s_waitcnt lgkmcnt(0)" ::: "memory");

    if (act){
      f32x4 gq = uscr[wv][m*4+g4];
      float gi = gq.x + nx.x, gf = gq.y + nx.y;
      float gg = gq.z + nx.z, go = gq.w + nx.w;
      float i_ = sigmoidf(gi), f_ = sigmoidf(gf);
      float g_ = tanh_fast(gg), o_ = sigmoidf(go);
      c = fmaf(f_, c, i_*g_);
      float h = o_ * tanh_fast(c);
      hbufS[(t+1)&1][unit] = (_Float16)h;
      if (GATED==0) hOutHalf[t*256+unit] = (_Float16)h;
      else          hOutF32 [t*256+unit] = h;
    }
    __syncthreads();                 // ONE barrier: h visible, global stores drained
    if (tid==0 && ((t&7)==7 || t==SEQ-1))
      __hip_atomic_store(prog,(unsigned)(t+1),__ATOMIC_RELEASE,__HIP_MEMORY_SCOPE_AGENT);
  }
}

// xw chunk worker (r10/r12/r13-proven); output layout [t][unit][gate]
__device__ void do_xw(int b, const h2* __restrict__ wih1T, const float* __restrict__ bs1,
                      const _Float16* __restrict__ h0h, float* __restrict__ xw1,
                      unsigned* sync)
{
  const int tid = threadIdx.x;
  const int t0 = 8*b;
  const int tend = (t0+8 < SEQ) ? t0+8 : SEQ;
  if (tid==0) waitge<32>(&sync[IDX_C0], (unsigned)tend);
  __syncthreads();
  const float bA = bs1[tid], bB = bs1[tid+512];
  const int r0 = tid, r1 = tid + 512;
  const int d0 = ((r0&255)<<2) + (r0>>8);
  const int d1 = ((r1&255)<<2) + (r1>>8);
#pragma unroll 1
  for (int t=t0;t<tend;++t){
    const uint4* hv4 = (const uint4*)(h0h + (size_t)t*256);
    float a0=bA, a1=bB;
    h2 pa0={0,0}, pb0={0,0}, pa1={0,0}, pb1={0,0};
#pragma unroll
    for (int q=0;q<32;++q){
      uint4 hv = hv4[q];
      h2 hx=u2h(hv.x), hy=u2h(hv.y), hz=u2h(hv.z), hw=u2h(hv.w);
      pa0 = pkfma(hx, wih1T[(4*q+0)*1024+r0], pa0);
      pb0 = pkfma(hy, wih1T[(4*q+1)*1024+r0], pb0);
      pa0 = pkfma(hz, wih1T[(4*q+2)*1024+r0], pa0);
      pb0 = pkfma(hw, wih1T[(4*q+3)*1024+r0], pb0);
      pa1 = pkfma(hx, wih1T[(4*q+0)*1024+r1], pa1);
      pb1 = pkfma(hy, wih1T[(4*q+1)*1024+r1], pb1);
      pa1 = pkfma(hz, wih1T[(4*q+2)*1024+r1], pa1);
      pb1 = pkfma(hw, wih1T[(4*q+3)*1024+r1], pb1);
      if ((q&3)==3){
        a0 += (float)pa0.x + (float)pa0.y + (float)pb0.x + (float)pb0.y;
        a1 += (float)pa1.x + (float)pa1.y + (float)pb1.x + (float)pb1.y;
        pa0={0,0}; pb0={0,0}; pa1={0,0}; pb1={0,0};
      }
    }
    xw1[(size_t)t*1024 + d0] = a0;
    xw1[(size_t)t*1024 + d1] = a1;
  }
  __syncthreads();
  if (tid==0)
    __hip_atomic_store(&sync[IDX_FLG + 32*b], 1u, __ATOMIC_RELEASE, __HIP_MEMORY_SCOPE_AGENT);
}

// W1 streamer (r10/r12/r13-proven)
__device__ void do_w1(int w, const float* __restrict__ W1, const float* __restrict__ b1,
                      const float* __restrict__ h1f, float* __restrict__ z1,
                      unsigned* sync, float* red)
{
  const int tid = threadIdx.x;
#pragma unroll 1
  for (int rr=0;rr<4;++rr){
    const int j = w*4 + rr;
    const float* wrow = W1 + (size_t)j*(SEQ*256);
    float acc = 0.f;
#pragma unroll 1
    for (int kc=0;kc<8;++kc){
      const int lo = kc*128, hi = (kc==7) ? SEQ : lo+128;
      if (tid==0) waitge<64>(&sync[IDX_C1], (unsigned)hi);
      __syncthreads();
      const float4* w4 = (const float4*)(wrow + lo*256);
      const float4* h4 = (const float4*)(h1f + lo*256);
      const int n4 = (hi-lo)*64;
      for (int q=tid; q<n4; q+=512){
        float4 a=w4[q], b=h4[q];
        acc=fmaf(a.x,b.x,acc); acc=fmaf(a.y,b.y,acc);
        acc=fmaf(a.z,b.z,acc); acc=fmaf(a.w,b.w,acc);
      }
      __syncthreads();
    }
    red[tid]=acc; __syncthreads();
    for (int s=256;s>0;s>>=1){ if(tid<s) red[tid]+=red[tid+s]; __syncthreads(); }
    if (tid==0) z1[j] = softplusf(red[0] + b1[j]);
    __syncthreads();
  }
  if (tid==0)
    __hip_atomic_fetch_add(&sync[IDX_CW1], 1u, __ATOMIC_RELEASE, __HIP_MEMORY_SCOPE_AGENT);
}

__device__ void do_head(const float* __restrict__ W2, const float* __restrict__ b2,
                        const float* __restrict__ W3, const float* __restrict__ b3,
                        const float* __restrict__ z1, const float* __restrict__ data,
                        float* __restrict__ out, unsigned* sync, float* red)
{
  const int tid = threadIdx.x;
  if (tid==0) waitge<64>(&sync[IDX_CW1], (unsigned)NW1);
  __syncthreads();
  if (tid<256) red[tid] = z1[tid];
  __syncthreads();
  if (tid<128){
    float acc = b2[tid];
#pragma unroll 4
    for (int kk=0;kk<256;++kk) acc = fmaf(W2[tid*256+kk], red[kk], acc);
    red[256+tid] = softplusf(acc);
  }
  __syncthreads();
  if (tid<4){
    float a = b3[tid];
#pragma unroll 4
    for (int kk=0;kk<128;++kk) a = fmaf(W3[tid*128+kk], red[256+kk], a);
    red[384+tid] = a;
  }
  __syncthreads();
  if (tid==0){
    float a=red[384], b=red[385], cc=red[386], d=red[387];
    float R=data[0], J=data[1];
#pragma unroll 1
    for (int t=0;t<SEQ;++t){
      float RJ=R*J;
      float Rn = R + DTC*(a*R - b*RJ);
      float Jn = J + DTC*(d*RJ - cc*J);
      out[2*t]=Rn; out[2*t+1]=Jn;
      R=Rn; J=Jn;
    }
  }
}

// roles: 0=L0 | 1=L1 | 2..126 xw | 127..190 W1 | 191 head. 512 thr, ~136KB LDS -> 1/CU.
__global__ __launch_bounds__(512,1)
void k_fused(const u32x4* __restrict__ aW0, const h2* __restrict__ wih1T,
             const u32x4* __restrict__ aW1, const float* __restrict__ bs1,
             const float* __restrict__ xw0, _Float16* h0h, float* xw1, float* h1f,
             float* z1, const float* __restrict__ W1, const float* __restrict__ b1,
             const float* __restrict__ W2, const float* __restrict__ b2,
             const float* __restrict__ W3, const float* __restrict__ b3,
             const float* __restrict__ data, float* out, unsigned* sync)
{
  __shared__ __align__(16) u32x4 aspill[8][2][8][64];   // 128 KB (LDS A-frags)
  __shared__ __align__(16) f32x4 uscr[8][32];           // 4 KB per-wave update scratch
  __shared__ __align__(16) _Float16 hbufS[2][256];      // 1 KB double-buffered h
  __shared__ float red[512];                            // 2 KB

  const int role = blockIdx.x;
  if (role == 0)
    do_layer<0>(aW0, xw0, h0h, nullptr, &sync[IDX_C0], sync, aspill, uscr, hbufS);
  else if (role == 1)
    do_layer<1>(aW1, xw1, nullptr, h1f, &sync[IDX_C1], sync, aspill, uscr, hbufS);
  else if (role < 2+NXW)
    do_xw(role-2, wih1T, bs1, h0h, xw1, sync);
  else if (role < 2+NXW+NW1)
    do_w1(role-(2+NXW), W1, b1, h1f, z1, sync, red);
  else
    do_head(W2, b2, W3, b3, z1, data, out, sync, red);
}

extern "C" void kernel_launch(void* const* d_in, const int* in_sizes, int n_in,
                              void* d_out, int out_size, void* d_ws, size_t ws_size,
                              hipStream_t stream){
  const float* X    = (const float*)d_in[0];
  const float* data = (const float*)d_in[1];
  const float* Wih0 = (const float*)d_in[2];
  const float* Whh0 = (const float*)d_in[3];
  const float* bih0 = (const float*)d_in[4];
  const float* bhh0 = (const float*)d_in[5];
  const float* Wih1 = (const float*)d_in[6];
  const float* Whh1 = (const float*)d_in[7];
  const float* bih1 = (const float*)d_in[8];
  const float* bhh1 = (const float*)d_in[9];
  const float* W1   = (const float*)d_in[10];
  const float* b1   = (const float*)d_in[11];
  const float* W2   = (const float*)d_in[12];
  const float* b2   = (const float*)d_in[13];
  const float* W3   = (const float*)d_in[14];
  const float* b3   = (const float*)d_in[15];
  float* out = (float*)d_out;

  char* w = (char*)d_ws;
  h2*       aW0c  = (h2*)(w + 0);              // 512 KB A-frag f16 (layer0)
  h2*       wih1T = (h2*)(w + 524288);         // 512 KB transposed f16
  h2*       aW1c  = (h2*)(w + 1048576);        // 512 KB A-frag f16 (layer1)
  float*    bs1   = (float*)(w + 1576960);     // 4 KB
  _Float16* h0h   = (_Float16*)(w + 1581056);  // 511,488 B
  float*    xw1   = (float*)(w + 2097152);     // 4,091,904 B  [t][unit][gate]
  float*    h1f   = (float*)(w + 6189056);     // 1,022,976 B
  float*    z1    = (float*)(w + 7212032);     // 1 KB
  unsigned* sync  = (unsigned*)(w + 7213056);  // 16 KB padded counters/flags
  float*    xw0   = (float*)(w + 7229440);     // 4,091,904 B  [t][unit][gate]

  k_init<<<1, 512, 0, stream>>>(sync);
  k_convert<<<5540, 256, 0, stream>>>(Whh0, Wih1, Whh1, Wih0, X,
                                      bih0, bhh0, bih1, bhh1,
                                      aW0c, wih1T, aW1c, bs1, xw0);
  k_fused<<<2+NXW+NW1+1, 512, 0, stream>>>((const u32x4*)aW0c, wih1T, (const u32x4*)aW1c,
                                           bs1, xw0, h0h, xw1, h1f, z1,
                                           W1, b1, W2, b2, W3, b3, data, out, sync);
}

// Round 15
// 1829.309 us; speedup vs baseline: 1.4878x; 1.4878x over previous
//
#include <hip/hip_runtime.h>

#define SEQ 999
#define DTC 0.01f
#define NXW 125
#define NW1 64
#define IDX_C0  0
#define IDX_C1  32
#define IDX_CW1 64
#define IDX_FLG 96
#define SYNC_DWORDS 4096
#define XW0B 395264          // k_convert: xw0 work starts at this flat index

typedef _Float16 h2 __attribute__((ext_vector_type(2)));
typedef unsigned u32x4 __attribute__((ext_vector_type(4)));
typedef float f32x4 __attribute__((ext_vector_type(4)));

__device__ __forceinline__ h2 u2h(unsigned u){ return __builtin_bit_cast(h2,u); }
__device__ __forceinline__ h2 pkfma(h2 a, h2 b, h2 c){ return __builtin_elementwise_fma(a,b,c); }

__device__ __forceinline__ float softplusf(float x){
  return fmaxf(x,0.f) + log1pf(__expf(-fabsf(x)));
}
__device__ __forceinline__ float sigmoidf(float x){ return 1.f/(1.f+__expf(-x)); }
__device__ __forceinline__ float tanh_fast(float x){
  float e = __expf(-2.f*x); return (1.f-e)/(1.f+e);
}

template<int SLP>
__device__ __forceinline__ void waitge(unsigned* p, unsigned v){
  if (__hip_atomic_load(p,__ATOMIC_RELAXED,__HIP_MEMORY_SCOPE_AGENT) < v){
    do { __builtin_amdgcn_s_sleep(SLP); }
    while (__hip_atomic_load(p,__ATOMIC_RELAXED,__HIP_MEMORY_SCOPE_AGENT) < v);
  }
  (void)__hip_atomic_load(p,__ATOMIC_ACQUIRE,__HIP_MEMORY_SCOPE_AGENT);
}

__global__ void k_init(unsigned* sync){
  for (int i=threadIdx.x; i<SYNC_DWORDS; i+=512) sync[i] = 0u;
}

// Whh -> MFMA A-frags, INTERLEAVED rows (r13-proven): tile T rows = units 4T..4T+3
// x gates i,f,g,o (rl: unit_local=rl>>2, gate=rl&3). k-mapping r11-r13-proven.
// wih1 -> TRANSPOSED (do_xw). xw0[t][unit][gate] precomputed.
__global__ void k_convert(const float* __restrict__ whh0, const float* __restrict__ wih1,
                          const float* __restrict__ whh1, const float* __restrict__ wih0,
                          const float* __restrict__ X,
                          const float* __restrict__ bih0, const float* __restrict__ bhh0,
                          const float* __restrict__ bih1, const float* __restrict__ bhh1,
                          h2* __restrict__ aW0, h2* __restrict__ wih1T, h2* __restrict__ aW1,
                          float* __restrict__ bs1, float* __restrict__ xw0){
  int o = blockIdx.x*256 + threadIdx.x;
  if (o < 131072){
    int f = o >> 8, rem = o & 255, l = rem >> 2, jp = rem & 3;
    int tile = f >> 3, q = f & 7;
    int rl = l & 15;
    int row = (rl & 3)*256 + tile*4 + (rl >> 2);
    int col = q*32 + ((l >> 4) << 3) + (jp << 1);
    const float* s = whh0 + row*256 + col;
    aW0[o] = h2{(_Float16)s[0], (_Float16)s[1]};
  } else if (o < 262144){
    int oo = o - 131072; int r = oo & 1023, c2 = oo >> 10;
    const float* s = wih1 + r*256 + 2*c2;
    wih1T[oo] = h2{(_Float16)s[0], (_Float16)s[1]};
  } else if (o < 393216){
    int oo = o - 262144;
    int f = oo >> 8, rem = oo & 255, l = rem >> 2, jp = rem & 3;
    int tile = f >> 3, q = f & 7;
    int rl = l & 15;
    int row = (rl & 3)*256 + tile*4 + (rl >> 2);
    int col = q*32 + ((l >> 4) << 3) + (jp << 1);
    const float* s = whh1 + row*256 + col;
    aW1[oo] = h2{(_Float16)s[0], (_Float16)s[1]};
  } else if (o < 394240){
    // spare
  } else if (o < XW0B){
    int r = o - 394240; bs1[r] = bih1[r] + bhh1[r];
  } else if (o < XW0B + SEQ*1024){
    int idx = o - XW0B;
    int t = idx >> 10, r = idx & 1023;
    int k = r >> 2, g = r & 3;
    int row = g*256 + k;
    float v = wih0[row*2]*X[2*t] + wih0[row*2+1]*X[2*t+1] + bih0[row] + bhh0[row];
    xw0[idx] = v;
  }
}

// ---- MFMA helpers (r13-proven) ----
#define MMA(ACC,AG,BQ)  asm volatile("v_mfma_f32_16x16x32_f16 %0, %1, %2, %0" \
  : "+v"(ACC) : "a"(AG), "v"(BQ))
#define MMV(ACC,AV,BQ)  asm volatile("v_mfma_f32_16x16x32_f16 %0, %1, %2, %0" \
  : "+v"(ACC), "+v"(AV) : "v"(BQ))
#define MML(ACC,W,BQ)   asm volatile("v_mfma_f32_16x16x32_f16 %0, %1, %2, %0" \
  : "+v"(ACC) : "v"(W), "v"(BQ))
#define MMAI(ACC,AG,BQ) asm volatile("v_mfma_f32_16x16x32_f16 %0, %1, %2, %3" \
  : "=&v"(ACC) : "a"(AG), "v"(BQ), "v"(zero4))
#define MMVI(ACC,AV,BQ) asm volatile("v_mfma_f32_16x16x32_f16 %0, %1, %2, %3" \
  : "=&v"(ACC), "+v"(AV) : "v"(BQ), "v"(zero4))
#define MMLI(ACC,W,BQ)  asm volatile("v_mfma_f32_16x16x32_f16 %0, %1, %2, %3" \
  : "=&v"(ACC) : "v"(W), "v"(BQ), "v"(zero4))

#define QF() do{                                                   \
  u32x4 Bq = *(const u32x4*)(hbp);                                 \
  u32x4 w6 = aspill[wv][0][0][lane];                               \
  u32x4 w7 = aspill[wv][1][0][lane];                               \
  MMAI(ac0,agA[0][0],Bq); MMAI(ac1,agA[1][0],Bq);                  \
  MMAI(ac2,agA[2][0],Bq); MMAI(ac3,agA[3][0],Bq);                  \
  MMVI(ac4,avA[0][0],Bq); MMVI(ac5,avA[1][0],Bq);                  \
  MMLI(ac6,w6,Bq);        MMLI(ac7,w7,Bq);                         \
}while(0)
#define QN(Q) do{                                                  \
  u32x4 Bq = *(const u32x4*)(hbp + (Q)*64);                        \
  u32x4 w6 = aspill[wv][0][Q][lane];                               \
  u32x4 w7 = aspill[wv][1][Q][lane];                               \
  MMA(ac0,agA[0][Q],Bq); MMA(ac1,agA[1][Q],Bq);                    \
  MMA(ac2,agA[2][Q],Bq); MMA(ac3,agA[3][Q],Bq);                    \
  MMV(ac4,avA[0][Q],Bq); MMV(ac5,avA[1][Q],Bq);                    \
  MML(ac6,w6,Bq);        MML(ac7,w7,Bq);                           \
}while(0)

// ===== LSTM layer, ONE CU, MFMA, single barrier/step (r13 structure).
// 512 thr / 8 waves; wave owns tiles wv*8..+7 = units wv*32..+31 (interleaved gates).
// Residency (r13-proven budget: 128 arch + 128 AGPR = 256 = 2 waves/SIMD):
// tiles 0-3 AGPR, 4-5 arch VGPR (tied), 6-7 LDS.
// UPDATE IS IN-REGISTER: lane (m,g4) holds unit (wv*8+tt)*4+g4's gates in ac_tt
// (D-layout: reg r = gate r of unit_local g4; 16 m-columns redundant). Thread
// (m<8,g4) -> unit wv*32+m*4+g4 needs ac_m: 3-level cndmask tree, no LDS round-trip.
template<int GATED>   // 0: L0 (xw0), 1: L1 (xw1, chunk-flag gated)
__device__ void do_layer(const u32x4* __restrict__ wA, const float* __restrict__ xw,
                         _Float16* __restrict__ hOutHalf, float* __restrict__ hOutF32,
                         unsigned* prog, unsigned* sync,
                         u32x4 (*aspill)[2][8][64], _Float16 (*hbufS)[256])
{
  const int tid  = threadIdx.x;
  const int lane = tid & 63;
  const int wv   = tid >> 6;
  const int m    = lane & 15;
  const int g4   = lane >> 4;
  const bool act = m < 8;
  const int unit = wv*32 + m*4 + g4;          // valid when act

  u32x4 agA[4][8], avA[2][8];
#pragma unroll
  for (int tt=0;tt<4;++tt)
#pragma unroll
    for (int q=0;q<8;++q)
      agA[tt][q] = wA[(size_t)(((wv*8+tt)*8+q)*64) + lane];
#pragma unroll
  for (int tt=0;tt<4;++tt)
#pragma unroll
    for (int q=0;q<8;++q) asm("" : "+a"(agA[tt][q]));
#pragma unroll
  for (int tt=0;tt<2;++tt)
#pragma unroll
    for (int q=0;q<8;++q){
      avA[tt][q] = wA[(size_t)(((wv*8+4+tt)*8+q)*64) + lane];
      asm("" : "+v"(avA[tt][q]));
    }
#pragma unroll
  for (int tt=0;tt<2;++tt)
#pragma unroll
    for (int q=0;q<8;++q)
      aspill[wv][tt][q][lane] = wA[(size_t)(((wv*8+6+tt)*8+q)*64) + lane];

  if (tid < 256) hbufS[0][tid] = (_Float16)0.f;
  __syncthreads();

  if (GATED){
    if (tid==0) waitge<2>(&sync[IDX_FLG+0], 1u);
    __syncthreads();
  }

  f32x4 zero4 = {0.f,0.f,0.f,0.f};
  asm("" : "+v"(zero4));

  const char* hbb = (const char*)&hbufS[0][0] + (g4<<4);
  float c = 0.f;

#pragma unroll 1
  for (int t=0;t<SEQ;++t){
    if (GATED && (t&7)==0 && t){
      if (tid==0) waitge<2>(&sync[IDX_FLG + (t>>3)*32], 1u);
      __syncthreads();
    }
    float4 nx = {0,0,0,0};
    if (act) nx = *(const float4*)&xw[(size_t)t*1024 + (unit<<2)];   // returns during mfma

    const char* hbp = hbb + ((t&1)<<9);
    f32x4 ac0, ac1, ac2, ac3, ac4, ac5, ac6, ac7;
    QF();
    QN(1); QN(2); QN(3); QN(4); QN(5); QN(6); QN(7);
    asm volatile("s_nop 7\n\ts_nop 7");

    if (act){
      // select ac_m in-register (7 f32x4 cndmask selects)
      const bool b0 = (m & 1), b1 = (m & 2), b2 = (m & 4);
      f32x4 t01 = b0 ? ac1 : ac0;
      f32x4 t23 = b0 ? ac3 : ac2;
      f32x4 t45 = b0 ? ac5 : ac4;
      f32x4 t67 = b0 ? ac7 : ac6;
      f32x4 u0  = b1 ? t23 : t01;
      f32x4 u1  = b1 ? t67 : t45;
      f32x4 gq  = b2 ? u1  : u0;

      float gi = gq.x + nx.x, gf = gq.y + nx.y;
      float gg = gq.z + nx.z, go = gq.w + nx.w;
      float i_ = sigmoidf(gi), f_ = sigmoidf(gf);
      float g_ = tanh_fast(gg), o_ = sigmoidf(go);
      c = fmaf(f_, c, i_*g_);
      float h = o_ * tanh_fast(c);
      hbufS[(t+1)&1][unit] = (_Float16)h;
      if (GATED==0) hOutHalf[t*256+unit] = (_Float16)h;
      else          hOutF32 [t*256+unit] = h;
    }
    __syncthreads();                 // ONE barrier: h visible, global stores drained
    if (tid==0 && ((t&7)==7 || t==SEQ-1))
      __hip_atomic_store(prog,(unsigned)(t+1),__ATOMIC_RELEASE,__HIP_MEMORY_SCOPE_AGENT);
  }
}

// xw chunk worker (r10-r13-proven); output layout [t][unit][gate]
__device__ void do_xw(int b, const h2* __restrict__ wih1T, const float* __restrict__ bs1,
                      const _Float16* __restrict__ h0h, float* __restrict__ xw1,
                      unsigned* sync)
{
  const int tid = threadIdx.x;
  const int t0 = 8*b;
  const int tend = (t0+8 < SEQ) ? t0+8 : SEQ;
  if (tid==0) waitge<32>(&sync[IDX_C0], (unsigned)tend);
  __syncthreads();
  const float bA = bs1[tid], bB = bs1[tid+512];
  const int r0 = tid, r1 = tid + 512;
  const int d0 = ((r0&255)<<2) + (r0>>8);
  const int d1 = ((r1&255)<<2) + (r1>>8);
#pragma unroll 1
  for (int t=t0;t<tend;++t){
    const uint4* hv4 = (const uint4*)(h0h + (size_t)t*256);
    float a0=bA, a1=bB;
    h2 pa0={0,0}, pb0={0,0}, pa1={0,0}, pb1={0,0};
#pragma unroll
    for (int q=0;q<32;++q){
      uint4 hv = hv4[q];
      h2 hx=u2h(hv.x), hy=u2h(hv.y), hz=u2h(hv.z), hw=u2h(hv.w);
      pa0 = pkfma(hx, wih1T[(4*q+0)*1024+r0], pa0);
      pb0 = pkfma(hy, wih1T[(4*q+1)*1024+r0], pb0);
      pa0 = pkfma(hz, wih1T[(4*q+2)*1024+r0], pa0);
      pb0 = pkfma(hw, wih1T[(4*q+3)*1024+r0], pb0);
      pa1 = pkfma(hx, wih1T[(4*q+0)*1024+r1], pa1);
      pb1 = pkfma(hy, wih1T[(4*q+1)*1024+r1], pb1);
      pa1 = pkfma(hz, wih1T[(4*q+2)*1024+r1], pa1);
      pb1 = pkfma(hw, wih1T[(4*q+3)*1024+r1], pb1);
      if ((q&3)==3){
        a0 += (float)pa0.x + (float)pa0.y + (float)pb0.x + (float)pb0.y;
        a1 += (float)pa1.x + (float)pa1.y + (float)pb1.x + (float)pb1.y;
        pa0={0,0}; pb0={0,0}; pa1={0,0}; pb1={0,0};
      }
    }
    xw1[(size_t)t*1024 + d0] = a0;
    xw1[(size_t)t*1024 + d1] = a1;
  }
  __syncthreads();
  if (tid==0)
    __hip_atomic_store(&sync[IDX_FLG + 32*b], 1u, __ATOMIC_RELEASE, __HIP_MEMORY_SCOPE_AGENT);
}

// W1 streamer (r10-r13-proven)
__device__ void do_w1(int w, const float* __restrict__ W1, const float* __restrict__ b1,
                      const float* __restrict__ h1f, float* __restrict__ z1,
                      unsigned* sync, float* red)
{
  const int tid = threadIdx.x;
#pragma unroll 1
  for (int rr=0;rr<4;++rr){
    const int j = w*4 + rr;
    const float* wrow = W1 + (size_t)j*(SEQ*256);
    float acc = 0.f;
#pragma unroll 1
    for (int kc=0;kc<8;++kc){
      const int lo = kc*128, hi = (kc==7) ? SEQ : lo+128;
      if (tid==0) waitge<64>(&sync[IDX_C1], (unsigned)hi);
      __syncthreads();
      const float4* w4 = (const float4*)(wrow + lo*256);
      const float4* h4 = (const float4*)(h1f + lo*256);
      const int n4 = (hi-lo)*64;
      for (int q=tid; q<n4; q+=512){
        float4 a=w4[q], b=h4[q];
        acc=fmaf(a.x,b.x,acc); acc=fmaf(a.y,b.y,acc);
        acc=fmaf(a.z,b.z,acc); acc=fmaf(a.w,b.w,acc);
      }
      __syncthreads();
    }
    red[tid]=acc; __syncthreads();
    for (int s=256;s>0;s>>=1){ if(tid<s) red[tid]+=red[tid+s]; __syncthreads(); }
    if (tid==0) z1[j] = softplusf(red[0] + b1[j]);
    __syncthreads();
  }
  if (tid==0)
    __hip_atomic_fetch_add(&sync[IDX_CW1], 1u, __ATOMIC_RELEASE, __HIP_MEMORY_SCOPE_AGENT);
}

__device__ void do_head(const float* __restrict__ W2, const float* __restrict__ b2,
                        const float* __restrict__ W3, const float* __restrict__ b3,
                        const float* __restrict__ z1, const float* __restrict__ data,
                        float* __restrict__ out, unsigned* sync, float* red)
{
  const int tid = threadIdx.x;
  if (tid==0) waitge<64>(&sync[IDX_CW1], (unsigned)NW1);
  __syncthreads();
  if (tid<256) red[tid] = z1[tid];
  __syncthreads();
  if (tid<128){
    float acc = b2[tid];
#pragma unroll 4
    for (int kk=0;kk<256;++kk) acc = fmaf(W2[tid*256+kk], red[kk], acc);
    red[256+tid] = softplusf(acc);
  }
  __syncthreads();
  if (tid<4){
    float a = b3[tid];
#pragma unroll 4
    for (int kk=0;kk<128;++kk) a = fmaf(W3[tid*128+kk], red[256+kk], a);
    red[384+tid] = a;
  }
  __syncthreads();
  if (tid==0){
    float a=red[384], b=red[385], cc=red[386], d=red[387];
    float R=data[0], J=data[1];
#pragma unroll 1
    for (int t=0;t<SEQ;++t){
      float RJ=R*J;
      float Rn = R + DTC*(a*R - b*RJ);
      float Jn = J + DTC*(d*RJ - cc*J);
      out[2*t]=Rn; out[2*t+1]=Jn;
      R=Rn; J=Jn;
    }
  }
}

// roles: 0=L0 | 1=L1 | 2..126 xw | 127..190 W1 | 191 head. 512 thr, ~132KB LDS -> 1/CU.
__global__ __launch_bounds__(512,1)
void k_fused(const u32x4* __restrict__ aW0, const h2* __restrict__ wih1T,
             const u32x4* __restrict__ aW1, const float* __restrict__ bs1,
             const float* __restrict__ xw0, _Float16* h0h, float* xw1, float* h1f,
             float* z1, const float* __restrict__ W1, const float* __restrict__ b1,
             const float* __restrict__ W2, const float* __restrict__ b2,
             const float* __restrict__ W3, const float* __restrict__ b3,
             const float* __restrict__ data, float* out, unsigned* sync)
{
  __shared__ __align__(16) u32x4 aspill[8][2][8][64];   // 128 KB (LDS A-frags)
  __shared__ __align__(16) _Float16 hbufS[2][256];      // 1 KB double-buffered h
  __shared__ float red[512];                            // 2 KB

  const int role = blockIdx.x;
  if (role == 0)
    do_layer<0>(aW0, xw0, h0h, nullptr, &sync[IDX_C0], sync, aspill, hbufS);
  else if (role == 1)
    do_layer<1>(aW1, xw1, nullptr, h1f, &sync[IDX_C1], sync, aspill, hbufS);
  else if (role < 2+NXW)
    do_xw(role-2, wih1T, bs1, h0h, xw1, sync);
  else if (role < 2+NXW+NW1)
    do_w1(role-(2+NXW), W1, b1, h1f, z1, sync, red);
  else
    do_head(W2, b2, W3, b3, z1, data, out, sync, red);
}

extern "C" void kernel_launch(void* const* d_in, const int* in_sizes, int n_in,
                              void* d_out, int out_size, void* d_ws, size_t ws_size,
                              hipStream_t stream){
  const float* X    = (const float*)d_in[0];
  const float* data = (const float*)d_in[1];
  const float* Wih0 = (const float*)d_in[2];
  const float* Whh0 = (const float*)d_in[3];
  const float* bih0 = (const float*)d_in[4];
  const float* bhh0 = (const float*)d_in[5];
  const float* Wih1 = (const float*)d_in[6];
  const float* Whh1 = (const float*)d_in[7];
  const float* bih1 = (const float*)d_in[8];
  const float* bhh1 = (const float*)d_in[9];
  const float* W1   = (const float*)d_in[10];
  const float* b1   = (const float*)d_in[11];
  const float* W2   = (const float*)d_in[12];
  const float* b2   = (const float*)d_in[13];
  const float* W3   = (const float*)d_in[14];
  const float* b3   = (const float*)d_in[15];
  float* out = (float*)d_out;

  char* w = (char*)d_ws;
  h2*       aW0c  = (h2*)(w + 0);              // 512 KB A-frag f16 (layer0)
  h2*       wih1T = (h2*)(w + 524288);         // 512 KB transposed f16
  h2*       aW1c  = (h2*)(w + 1048576);        // 512 KB A-frag f16 (layer1)
  float*    bs1   = (float*)(w + 1576960);     // 4 KB
  _Float16* h0h   = (_Float16*)(w + 1581056);  // 511,488 B
  float*    xw1   = (float*)(w + 2097152);     // 4,091,904 B  [t][unit][gate]
  float*    h1f   = (float*)(w + 6189056);     // 1,022,976 B
  float*    z1    = (float*)(w + 7212032);     // 1 KB
  unsigned* sync  = (unsigned*)(w + 7213056);  // 16 KB padded counters/flags
  float*    xw0   = (float*)(w + 7229440);     // 4,091,904 B  [t][unit][gate]

  k_init<<<1, 512, 0, stream>>>(sync);
  k_convert<<<5540, 256, 0, stream>>>(Whh0, Wih1, Whh1, Wih0, X,
                                      bih0, bhh0, bih1, bhh1,
                                      aW0c, wih1T, aW1c, bs1, xw0);
  k_fused<<<2+NXW+NW1+1, 512, 0, stream>>>((const u32x4*)aW0c, wih1T, (const u32x4*)aW1c,
                                           bs1, xw0, h0h, xw1, h1f, z1,
                                           W1, b1, W2, b2, W3, b3, data, out, sync);
}